// Round 5
// baseline (199.308 us; speedup 1.0000x reference)
//
#include <hip/hip_runtime.h>
#include <math.h>

#define D_MODEL 1024
#define NUM_EXPERTS 8
#define TOP_K 2
#define LPG 16                       // lanes per group
#define GTOK 4                       // tokens per group (W-read amortization)
#define TOKENS_PER_WAVE 16           // (64/LPG) groups * GTOK
#define WAVES_PER_BLOCK 4
#define TOKENS_PER_BLOCK (TOKENS_PER_WAVE * WAVES_PER_BLOCK)  // 64

typedef float f4 __attribute__((ext_vector_type(4)));

// R5: lane = g*16 + l. Group g owns tokens tok0..tok0+3; lane l covers
// d = l*4 + kk*64 (kk=0..15). Each W ds_read_b128 feeds 4 tokens' FMAs ->
// LDS wave-insts/CU drop 4x vs R4 (4096 -> 1024, ~5us). 2-deep software
// pipeline on x chunks keeps ~8 loads in flight per lane (vmcnt never 0
// inside the loop). Grid 512 -> 2 blocks/CU, 8 waves/CU; HBM-bound ~21us.
__global__ __launch_bounds__(256) void gating_kernel(
    const float* __restrict__ x, const float* __restrict__ W,
    const float* __restrict__ b, float* __restrict__ out_w,
    float* __restrict__ out_idx, int n_tokens)
{
    __shared__ float Wlds[NUM_EXPERTS * D_MODEL];  // 32 KB

    {   // stage W: 2048 f4 across 256 threads -> 8 each
        const f4* Wg = (const f4*)W;
        f4* Ws = (f4*)Wlds;
        const int tid = threadIdx.x;
#pragma unroll
        for (int i = 0; i < (NUM_EXPERTS * D_MODEL / 4) / 256; ++i)
            Ws[tid + i * 256] = Wg[tid + i * 256];
    }
    __syncthreads();

    const int wave = threadIdx.x >> 6;
    const int lane = threadIdx.x & 63;
    const int g = lane >> 4;         // group 0..3
    const int l = lane & 15;         // lane-in-group
    const int tok0 = blockIdx.x * TOKENS_PER_BLOCK + wave * TOKENS_PER_WAVE + g * GTOK;
    if (tok0 >= n_tokens) return;

    // f4 view: token t row base = tok0*256 + t*256; lane covers f4 idx l + kk*16
    const f4* xb = (const f4*)x + (size_t)tok0 * (D_MODEL / 4) + l;
    const f4* Wf = (const f4*)Wlds + l;

    float acc[GTOK][NUM_EXPERTS];
#pragma unroll
    for (int t = 0; t < GTOK; ++t)
#pragma unroll
        for (int e = 0; e < NUM_EXPERTS; ++e) acc[t][e] = 0.f;

    // 8 chunks of 2 kk each; double-buffered prefetch.
    f4 buf[2][GTOK * 2];
#pragma unroll
    for (int t = 0; t < GTOK; ++t)
#pragma unroll
        for (int j = 0; j < 2; ++j)
            buf[0][t * 2 + j] = __builtin_nontemporal_load(xb + t * 256 + j * 16);

#pragma unroll
    for (int c = 0; c < 8; ++c) {
        const int cur = c & 1, nxt = cur ^ 1;
        if (c < 7) {
#pragma unroll
            for (int t = 0; t < GTOK; ++t)
#pragma unroll
                for (int j = 0; j < 2; ++j)
                    buf[nxt][t * 2 + j] = __builtin_nontemporal_load(
                        xb + t * 256 + ((c + 1) * 2 + j) * 16);
        }
#pragma unroll
        for (int e = 0; e < NUM_EXPERTS; ++e) {
#pragma unroll
            for (int j = 0; j < 2; ++j) {
                const f4 wv = Wf[e * 256 + (c * 2 + j) * 16];
#pragma unroll
                for (int t = 0; t < GTOK; ++t) {
                    const f4 xv = buf[cur][t * 2 + j];
                    acc[t][e] += xv.x * wv.x + xv.y * wv.y + xv.z * wv.z + xv.w * wv.w;
                }
            }
        }
    }

    // Reduce across the 16 lanes of the group (4 butterfly steps), add bias.
#pragma unroll
    for (int t = 0; t < GTOK; ++t)
#pragma unroll
        for (int e = 0; e < NUM_EXPERTS; ++e) {
            float v = acc[t][e];
            v += __shfl_xor(v, 1, 64);
            v += __shfl_xor(v, 2, 64);
            v += __shfl_xor(v, 4, 64);
            v += __shfl_xor(v, 8, 64);
            acc[t][e] = v + b[e];    // b[e]: thread-uniform -> s_load
        }

    // Each lane finishes one token: t = l>>2, role r = l&3.
    const int t = l >> 2;
    const int r = l & 3;
    const int token = tok0 + t;

    float v0 = -INFINITY, v1 = -INFINITY;
    int i0 = 0, i1 = 0;
#pragma unroll
    for (int e = 0; e < NUM_EXPERTS; ++e) {
        float v = acc[t][e];
        // strict > keeps lowest index on ties, matching jax.lax.top_k
        if (v > v0) { v1 = v0; i1 = i0; v0 = v; i0 = e; }
        else if (v > v1) { v1 = v; i1 = e; }
    }
    const float e1 = expf(v1 - v0);
    const float w0 = 1.f / (1.f + e1);
    const float w1 = e1 * w0;

    if (r < 2) {
        const int base = r * 4;
        f4 v4;
        v4.x = (base + 0 == i0) ? w0 : ((base + 0 == i1) ? w1 : 0.f);
        v4.y = (base + 1 == i0) ? w0 : ((base + 1 == i1) ? w1 : 0.f);
        v4.z = (base + 2 == i0) ? w0 : ((base + 2 == i1) ? w1 : 0.f);
        v4.w = (base + 3 == i0) ? w0 : ((base + 3 == i1) ? w1 : 0.f);
        ((f4*)(out_w + (size_t)token * NUM_EXPERTS))[r] = v4;
    } else if (r == 2) {
        *(float2*)(out_idx + (size_t)token * TOP_K) =
            make_float2((float)i0, (float)i1);
    }
}

extern "C" void kernel_launch(void* const* d_in, const int* in_sizes, int n_in,
                              void* d_out, int out_size, void* d_ws, size_t ws_size,
                              hipStream_t stream) {
    const float* x = (const float*)d_in[0];
    const float* W = (const float*)d_in[1];
    const float* b = (const float*)d_in[2];
    float* out = (float*)d_out;

    const int n_tokens = in_sizes[0] / D_MODEL;              // 32768
    float* out_w   = out;                                    // [n_tokens, 8]
    float* out_idx = out + (size_t)n_tokens * NUM_EXPERTS;   // [n_tokens, 2] as float

    const int grid = (n_tokens + TOKENS_PER_BLOCK - 1) / TOKENS_PER_BLOCK;  // 512
    gating_kernel<<<grid, 256, 0, stream>>>(x, W, b, out_w, out_idx, n_tokens);
}